// Round 5
// baseline (469.376 us; speedup 1.0000x reference)
//
#include <hip/hip_runtime.h>
#include <math.h>

#define N 8192
#define D 64
#define KS 4
#define LOG2E 1.4426950408889634f

typedef _Float16 half_t;
typedef _Float16 f16x8 __attribute__((ext_vector_type(8)));
typedef _Float16 f16x4 __attribute__((ext_vector_type(4)));
typedef float f32x4 __attribute__((ext_vector_type(4)));

#define MFMA32(a, b, c) __builtin_amdgcn_mfma_f32_16x16x32_f16((a), (b), (c), 0, 0, 0)

// Fragment-major layouts (hot-loop loads are base + lane*16B):
//  Qf,Kf [tile32][ks][tau][hl][lane][8] : elem (row=tile*32+tau*16+c16, col=ks*32+quad*8+j)
//  Zf    [tile32][dt][lane][8]          : elem (row=tile*32+quad*8+j, d=dt*16+c16)  HI only
//  XYf   [tile16][ks][lane][8]          : elem (row=tile*16+c16, col=ks*32+quad*8+j) HI only
// where lane = quad*16 + c16.

// MEASUREMENT ROUND (R5): exact R4 kernels; attn_kernel launched TWICE.
// Second launch rewrites identical values -> bit-identical output.
// attn_time = dur_us - 386.2 (R4 baseline, same code path otherwise).

// ---------------------------------------------------------------------------
// K1: Qf = (X@Wq)*0.125*log2e, Kf = X@Wk, both f16 hi/lo frag-major.
// (EXACT R0 version — rr-outer. k-outer variant measured as part of a +23us
// pair in R2/R3; parked.)
// ---------------------------------------------------------------------------
__global__ __launch_bounds__(256) void proj_kernel(
    const float* __restrict__ Wq, const float* __restrict__ Wk,
    const float* __restrict__ X, const float* __restrict__ Y,
    half_t* __restrict__ Qfx, half_t* __restrict__ Qfy,
    half_t* __restrict__ Kfx, half_t* __restrict__ Kfy)
{
    __shared__ float sWq[64][64];
    __shared__ float sWk[64][64];
    __shared__ float sIn[16][64];
    const int t = threadIdx.x;
#pragma unroll
    for (int p = 0; p < 16; ++p) {
        int idx = p * 256 + t;
        sWq[idx >> 6][idx & 63] = Wq[idx];
        sWk[idx >> 6][idx & 63] = Wk[idx];
    }
    const int R0 = blockIdx.x * 16;
    const float* src; half_t* dqf; half_t* dkf; int r0;
    if (R0 < N) { src = X; dqf = Qfx; dkf = Kfx; r0 = R0; }
    else        { src = Y; dqf = Qfy; dkf = Kfy; r0 = R0 - N; }
#pragma unroll
    for (int p = 0; p < 4; ++p) {
        int idx = p * 256 + t;
        sIn[idx >> 6][idx & 63] = src[(size_t)r0 * D + idx];
    }
    __syncthreads();
    const int c = t & 63;
    const int rb = t >> 6;
    const int ksi = c >> 5, quadi = (c >> 3) & 3, j = c & 7;
#pragma unroll
    for (int rr = 0; rr < 4; ++rr) {
        int r = rr * 4 + rb;
        float aq = 0.f, ak = 0.f;
#pragma unroll
        for (int k = 0; k < 64; ++k) {
            float xv = sIn[r][k];
            aq = fmaf(xv, sWq[k][c], aq);
            ak = fmaf(xv, sWk[k][c], ak);
        }
        aq *= (0.125f * LOG2E);
        int rg = r0 + r;
        int tile = rg >> 5, tau = (rg >> 4) & 1, c16l = rg & 15;
        size_t idx = (size_t)tile * 4096 + ksi * 2048 + tau * 1024
                   + (quadi * 16 + c16l) * 8 + j;
        half_t qhh = (half_t)aq;
        dqf[idx]       = qhh;
        dqf[idx + 512] = (half_t)(aq - (float)qhh);
        half_t khh = (half_t)ak;
        dkf[idx]       = khh;
        dkf[idx + 512] = (half_t)(ak - (float)khh);
    }
}

// ---------------------------------------------------------------------------
// K2: Zf prep (transposed input, f16 HI only, frag-major). grid (N/32, 2).
// ---------------------------------------------------------------------------
__global__ __launch_bounds__(256) void ztprep_kernel(
    const float* __restrict__ X, const float* __restrict__ Y,
    half_t* __restrict__ Zfx, half_t* __restrict__ Zfy)
{
    const int t = threadIdx.x;
    const int tile = blockIdx.x;
    const float* src = blockIdx.y ? Y : X;
    half_t* dst = blockIdx.y ? Zfy : Zfx;
    const int dt = t >> 6, lane = t & 63;
    const int quad = lane >> 4, c16 = lane & 15;
    f16x8 h;
#pragma unroll
    for (int j = 0; j < 8; ++j)
        h[j] = (half_t)src[(size_t)(tile * 32 + quad * 8 + j) * D + dt * 16 + c16];
    *(f16x8*)&dst[(size_t)tile * 2048 + dt * 512 + lane * 8] = h;
}

// ---------------------------------------------------------------------------
// K3: flash attention — R4 version (R0 structure + s_setprio around MFMA
// clusters). 4-wave 256-thread blocks, 2/CU, register ping-pong K prefetch,
// zero barriers. Numerics bit-identical to R0.
// ---------------------------------------------------------------------------
__global__ __launch_bounds__(256, 2) void attn_kernel(
    const half_t* __restrict__ Qfx, const half_t* __restrict__ Qfy,
    const half_t* __restrict__ Kfx, const half_t* __restrict__ Kfy,
    const half_t* __restrict__ Zfx, const half_t* __restrict__ Zfy,
    half_t* __restrict__ Opart, float* __restrict__ mpart, float* __restrict__ lpart)
{
    const int side = blockIdx.y;
    const half_t* Qf = side ? Qfy : Qfx;
    const half_t* Kf = side ? Kfy : Kfx;
    const half_t* Zf = side ? Zfy : Zfx;
    const int t = threadIdx.x, w = t >> 6, lane = t & 63;
    const int c16 = lane & 15, quad = lane >> 4;
    const int q0 = blockIdx.x * 128 + w * 32;
    const int tile0 = blockIdx.z * (N / KS / 32);
    const int ITERS = (N / KS) / 32;   // 64

    __shared__ half_t Pbuf[4][32][40];   // [wave][q][kv(+pad)] hi only
    half_t (*Phi)[40] = Pbuf[w];

    f16x8 qh[2][2], ql[2][2];   // [qg][ks]
    {
        const half_t* qb = Qf + (size_t)(q0 >> 5) * 4096 + lane * 8;
#pragma unroll
        for (int ks = 0; ks < 2; ++ks)
#pragma unroll
            for (int qg = 0; qg < 2; ++qg) {
                qh[qg][ks] = *(const f16x8*)&qb[ks * 2048 + qg * 1024];
                ql[qg][ks] = *(const f16x8*)&qb[ks * 2048 + qg * 1024 + 512];
            }
    }

    f32x4 ot[4][2] = {};      // O^T accumulators [dt][qg]
    f32x4 lacc[2] = {};       // l accumulators via ones-row MFMA
    float m_run[2] = {-INFINITY, -INFINITY};
    f16x8 ones;
#pragma unroll
    for (int i = 0; i < 8; ++i) ones[i] = (half_t)1.0f;

    f16x8 kAh[2][2], kAl[2][2], kBh[2][2], kBl[2][2];   // ping-pong K frags
    f32x4 stA[2][2], stB[2][2];                          // double-buffered S^T

    auto loadK = [&](int tile, f16x8 (&kh)[2][2], f16x8 (&kl)[2][2]) {
        const half_t* b = Kf + (size_t)tile * 4096 + lane * 8;
#pragma unroll
        for (int ks = 0; ks < 2; ++ks)
#pragma unroll
            for (int tau = 0; tau < 2; ++tau) {
                kh[ks][tau] = *(const f16x8*)&b[ks * 2048 + tau * 1024];
                kl[ks][tau] = *(const f16x8*)&b[ks * 2048 + tau * 1024 + 512];
            }
    };
    auto doS = [&](f32x4 (&st)[2][2], f16x8 (&kh)[2][2], f16x8 (&kl)[2][2]) {
        const f32x4 zero = {};
#pragma unroll
        for (int qg = 0; qg < 2; ++qg)
#pragma unroll
            for (int tau = 0; tau < 2; ++tau) st[qg][tau] = zero;
        __builtin_amdgcn_s_setprio(1);
#pragma unroll
        for (int ks = 0; ks < 2; ++ks)
#pragma unroll
            for (int tau = 0; tau < 2; ++tau)
#pragma unroll
                for (int qg = 0; qg < 2; ++qg) {
                    st[qg][tau] = MFMA32(kh[ks][tau], qh[qg][ks], st[qg][tau]);
                    st[qg][tau] = MFMA32(kh[ks][tau], ql[qg][ks], st[qg][tau]);
                    st[qg][tau] = MFMA32(kl[ks][tau], qh[qg][ks], st[qg][tau]);
                }
        __builtin_amdgcn_s_setprio(0);
    };

    auto body = [&](int tt, f32x4 (&stCur)[2][2], f32x4 (&stNext)[2][2],
                    f16x8 (&kNh)[2][2], f16x8 (&kNl)[2][2],
                    f16x8 (&kRh)[2][2], f16x8 (&kRl)[2][2]) {
        if (tt + 1 < ITERS) doS(stNext, kNh, kNl);           // S(t+1) in background
        if (tt + 2 < ITERS) loadK(tile0 + tt + 2, kRh, kRl); // K(t+2) in flight
        const half_t* zb = Zf + (size_t)(tile0 + tt) * 2048 + lane * 8;
        f16x8 zh[4];
#pragma unroll
        for (int dt = 0; dt < 4; ++dt)
            zh[dt] = *(const f16x8*)&zb[dt * 512];
        // ---- online softmax (exp2 domain), P hi-only ----
#pragma unroll
        for (int qg = 0; qg < 2; ++qg) {
            float mt = fmaxf(fmaxf(fmaxf(stCur[qg][0][0], stCur[qg][0][1]),
                                   fmaxf(stCur[qg][0][2], stCur[qg][0][3])),
                             fmaxf(fmaxf(stCur[qg][1][0], stCur[qg][1][1]),
                                   fmaxf(stCur[qg][1][2], stCur[qg][1][3])));
            mt = fmaxf(mt, __shfl_xor(mt, 16));
            mt = fmaxf(mt, __shfl_xor(mt, 32));
            float mn = fmaxf(m_run[qg], mt);
            float al = exp2f(m_run[qg] - mn);
            m_run[qg] = mn;
#pragma unroll
            for (int tau = 0; tau < 2; ++tau) {
                f16x4 h4;
#pragma unroll
                for (int r = 0; r < 4; ++r)
                    h4[r] = (half_t)exp2f(stCur[qg][tau][r] - mn);
                *(f16x4*)&Phi[16 * qg + c16][16 * tau + 4 * quad] = h4;
            }
            lacc[qg] *= al;
#pragma unroll
            for (int dt = 0; dt < 4; ++dt) ot[dt][qg] *= al;
        }
        // ---- P B-frags from LDS, PV + l ----
        f16x8 pbh[2];
#pragma unroll
        for (int qg = 0; qg < 2; ++qg)
            pbh[qg] = *(const f16x8*)&Phi[16 * qg + c16][quad * 8];
        __builtin_amdgcn_s_setprio(1);
#pragma unroll
        for (int dt = 0; dt < 4; ++dt)
#pragma unroll
            for (int qg = 0; qg < 2; ++qg)
                ot[dt][qg] = MFMA32(zh[dt], pbh[qg], ot[dt][qg]);
#pragma unroll
        for (int qg = 0; qg < 2; ++qg)
            lacc[qg] = MFMA32(ones, pbh[qg], lacc[qg]);
        __builtin_amdgcn_s_setprio(0);
    };

    loadK(tile0, kAh, kAl);
    doS(stA, kAh, kAl);                         // S(0)
    if (ITERS > 1) loadK(tile0 + 1, kBh, kBl);  // K(1)
#pragma unroll 1
    for (int tt = 0; tt < ITERS; tt += 2) {
        body(tt,     stA, stB, kBh, kBl, kAh, kAl);
        body(tt + 1, stB, stA, kAh, kAl, kBh, kBl);
    }

    // epilogue: unnormalized O (f16, relative to m_run) + m, l partials (f32)
    const size_t obase = (size_t)(side * KS + blockIdx.z) * N;
#pragma unroll
    for (int qg = 0; qg < 2; ++qg) {
        int q = q0 + 16 * qg + c16;
#pragma unroll
        for (int dt = 0; dt < 4; ++dt) {
            f16x4 o4;
#pragma unroll
            for (int r = 0; r < 4; ++r) o4[r] = (half_t)ot[dt][qg][r];
            *(f16x4*)&Opart[(obase + q) * D + 16 * dt + 4 * quad] = o4;
        }
        if (quad == 0) {
            mpart[obase + q] = m_run[qg];
            lpart[obase + q] = lacc[qg][0];
        }
    }
}

// ---------------------------------------------------------------------------
// K4: combine split-K partials (f16) -> Xf/Yf f16 HI-only frag-major.
// ---------------------------------------------------------------------------
__global__ __launch_bounds__(256) void combine_kernel(
    const half_t* __restrict__ Opart, const float* __restrict__ mpart,
    const float* __restrict__ lpart,
    half_t* __restrict__ Xf, half_t* __restrict__ Yf,
    float* __restrict__ n2x, float* __restrict__ n2y)
{
    const int side = blockIdx.y;
    const int q = blockIdx.x * 16 + (threadIdx.x >> 4);
    const int d4 = (threadIdx.x & 15) * 4;
    float m[KS], l[KS];
#pragma unroll
    for (int s = 0; s < KS; ++s) {
        size_t b = (size_t)(side * KS + s) * N + q;
        m[s] = mpart[b]; l[s] = lpart[b];
    }
    float M = -INFINITY;
#pragma unroll
    for (int s = 0; s < KS; ++s) M = fmaxf(M, m[s]);
    float L = 0.f;
    f32x4 o = {0.f, 0.f, 0.f, 0.f};
#pragma unroll
    for (int s = 0; s < KS; ++s) {
        float sc = exp2f(m[s] - M);
        L += l[s] * sc;
        f16x4 p4 = *(const f16x4*)&Opart[((size_t)(side * KS + s) * N + q) * D + d4];
#pragma unroll
        for (int i = 0; i < 4; ++i) o[i] = fmaf((float)p4[i], sc, o[i]);
    }
    const float oscale = (side ? 1.0f : 2.0f * LOG2E) / L;
    f16x4 h4;
#pragma unroll
    for (int i = 0; i < 4; ++i) h4[i] = (half_t)(o[i] * oscale);
    float sq = 0.f;
#pragma unroll
    for (int i = 0; i < 4; ++i) { float hv = (float)h4[i]; sq = fmaf(hv, hv, sq); }
#pragma unroll
    for (int off = 1; off < 16; off <<= 1) sq += __shfl_xor(sq, off);
    half_t* dst = side ? Yf : Xf;
    float*  n2  = side ? n2y : n2x;
    if ((threadIdx.x & 15) == 0)
        n2[q] = side ? sq * LOG2E : sq * (0.25f / LOG2E);
    const int tile16 = q >> 4, c16l = q & 15;
    const int ksi = d4 >> 5, quadi = (d4 >> 3) & 3, j0 = d4 & 7;
    *(f16x4*)&dst[(size_t)tile16 * 1024 + ksi * 512 + (quadi * 16 + c16l) * 8 + j0] = h4;
}

// ---------------------------------------------------------------------------
// K5: RBF via single-term f16 MFMA (consistent-points numerics), frag-major
// loads. EXACT R0 version (A=X frag, B=Y frag, scalar stores).
// ---------------------------------------------------------------------------
__global__ __launch_bounds__(256, 4) void rbf_kernel(
    const half_t* __restrict__ Xf, const half_t* __restrict__ Yf,
    const float* __restrict__ n2x, const float* __restrict__ n2y,
    float* __restrict__ out)
{
    const int t = threadIdx.x, w = t >> 6, lane = t & 63;
    const int c16 = lane & 15, quad = lane >> 4;
    const int X0 = blockIdx.y * 128 + (w >> 1) * 64;
    const int Y0 = blockIdx.x * 128 + (w & 1) * 64;
    float ny[4];
    f32x4 nx4[4];
#pragma unroll
    for (int yt = 0; yt < 4; ++yt) ny[yt] = n2y[Y0 + 16 * yt + c16];
#pragma unroll
    for (int xt = 0; xt < 4; ++xt)
        nx4[xt] = *(const f32x4*)&n2x[X0 + 16 * xt + 4 * quad];

    const half_t* Xb = Xf + lane * 8;
    const half_t* Yb = Yf + lane * 8;
    f32x4 acc[4][4] = {};   // [xt][yt]
#pragma unroll
    for (int ks = 0; ks < 2; ++ks) {
        f16x8 bh[4];
#pragma unroll
        for (int yt = 0; yt < 4; ++yt)
            bh[yt] = *(const f16x8*)&Yb[(size_t)((Y0 >> 4) + yt) * 1024 + ks * 512];
#pragma unroll
        for (int xt = 0; xt < 4; ++xt) {
            f16x8 ah = *(const f16x8*)&Xb[(size_t)((X0 >> 4) + xt) * 1024 + ks * 512];
#pragma unroll
            for (int yt = 0; yt < 4; ++yt)
                acc[xt][yt] = MFMA32(ah, bh[yt], acc[xt][yt]);
        }
    }
#pragma unroll
    for (int xt = 0; xt < 4; ++xt)
#pragma unroll
        for (int r = 0; r < 4; ++r) {
            int xr = X0 + 16 * xt + 4 * quad + r;
            float nx = nx4[xt][r];
#pragma unroll
            for (int yt = 0; yt < 4; ++yt) {
                float v = exp2f(acc[xt][yt][r] - nx - ny[yt]);
                out[(size_t)xr * N + Y0 + 16 * yt + c16] = v;
            }
        }
}

// ---------------------------------------------------------------------------
extern "C" void kernel_launch(void* const* d_in, const int* in_sizes, int n_in,
                              void* d_out, int out_size, void* d_ws, size_t ws_size,
                              hipStream_t stream) {
    const float* Wq = (const float*)d_in[0];
    const float* Wk = (const float*)d_in[1];
    const float* x  = (const float*)d_in[2];
    const float* y  = (const float*)d_in[3];
    float* out = (float*)d_out;

    char* p = (char*)d_ws;
    size_t used = 0;
    auto alloc = [&](size_t bytes) -> void* {
        void* r = (void*)(p + used);
        used += (bytes + 255) & ~(size_t)255;
        return r;
    };
    half_t* Qfx = (half_t*)alloc((size_t)N * D * 2 * 2);   // hi+lo frag-major
    half_t* Qfy = (half_t*)alloc((size_t)N * D * 2 * 2);
    half_t* Kfx = (half_t*)alloc((size_t)N * D * 2 * 2);
    half_t* Kfy = (half_t*)alloc((size_t)N * D * 2 * 2);
    half_t* Zfx = (half_t*)alloc((size_t)N * D * 2);       // hi only
    half_t* Zfy = (half_t*)alloc((size_t)N * D * 2);
    half_t* Xf  = (half_t*)alloc((size_t)N * D * 2);       // hi only
    half_t* Yf  = (half_t*)alloc((size_t)N * D * 2);
    float*  n2x = (float*) alloc((size_t)N * 4);
    float*  n2y = (float*) alloc((size_t)N * 4);
    half_t* Opart = (half_t*)alloc((size_t)2 * KS * N * D * 2);   // f16 partials
    float*  mpart = (float*) alloc((size_t)2 * KS * N * 4);
    float*  lpart = (float*) alloc((size_t)2 * KS * N * 4);

    proj_kernel<<<dim3(2 * N / 16), 256, 0, stream>>>(Wq, Wk, x, y,
                                                      Qfx, Qfy, Kfx, Kfy);
    ztprep_kernel<<<dim3(N / 32, 2), 256, 0, stream>>>(x, y, Zfx, Zfy);
    // MEASUREMENT: attn launched twice. Second run rewrites identical values
    // (same inputs -> same outputs), so result is bit-identical to R4.
    // attn_time = dur_us(this round) - 386.2 (R4).
    attn_kernel<<<dim3(N / 128, 2, KS), 256, 0, stream>>>(
        Qfx, Qfy, Kfx, Kfy, Zfx, Zfy, Opart, mpart, lpart);
    attn_kernel<<<dim3(N / 128, 2, KS), 256, 0, stream>>>(
        Qfx, Qfy, Kfx, Kfy, Zfx, Zfy, Opart, mpart, lpart);
    combine_kernel<<<dim3(N / 16, 2), 256, 0, stream>>>(
        Opart, mpart, lpart, Xf, Yf, n2x, n2y);
    rbf_kernel<<<dim3(N / 128, N / 128), 256, 0, stream>>>(Xf, Yf, n2x, n2y, out);
}

// Round 6
// 421.590 us; speedup vs baseline: 1.1133x; 1.1133x over previous
//
#include <hip/hip_runtime.h>
#include <math.h>

#define N 8192
#define D 64
#define KS 4
#define LOG2E 1.4426950408889634f

typedef _Float16 half_t;
typedef _Float16 f16x8 __attribute__((ext_vector_type(8)));
typedef _Float16 f16x4 __attribute__((ext_vector_type(4)));
typedef float f32x4 __attribute__((ext_vector_type(4)));

#define MFMA32(a, b, c) __builtin_amdgcn_mfma_f32_16x16x32_f16((a), (b), (c), 0, 0, 0)

// Fragment-major layouts (hot-loop loads are base + lane*16B):
//  Qf,Kf [tile32][ks][tau][hl][lane][8] : elem (row=tile*32+tau*16+c16, col=ks*32+quad*8+j)
//  Zf    [tile32][dt][lane][8]          : elem (row=tile*32+quad*8+j, d=dt*16+c16)  HI only
//  XYf   [tile16][ks][lane][8]          : elem (row=tile*16+c16, col=ks*32+quad*8+j) HI only
// where lane = quad*16 + c16.

// MEASUREMENT ROUND (R6): exact R4 kernels; rbf_kernel launched TWICE.
// Second launch rewrites identical values -> bit-identical output.
// rbf_time = dur_us - 386.2 (R4 baseline, same code otherwise).
// Session ledger: R4=386.2 (best, anchor). attn=83 (R5). rbf=THIS ROUND.

// ---------------------------------------------------------------------------
// K1: Qf = (X@Wq)*0.125*log2e, Kf = X@Wk, both f16 hi/lo frag-major.
// (EXACT R0 version — rr-outer.)
// ---------------------------------------------------------------------------
__global__ __launch_bounds__(256) void proj_kernel(
    const float* __restrict__ Wq, const float* __restrict__ Wk,
    const float* __restrict__ X, const float* __restrict__ Y,
    half_t* __restrict__ Qfx, half_t* __restrict__ Qfy,
    half_t* __restrict__ Kfx, half_t* __restrict__ Kfy)
{
    __shared__ float sWq[64][64];
    __shared__ float sWk[64][64];
    __shared__ float sIn[16][64];
    const int t = threadIdx.x;
#pragma unroll
    for (int p = 0; p < 16; ++p) {
        int idx = p * 256 + t;
        sWq[idx >> 6][idx & 63] = Wq[idx];
        sWk[idx >> 6][idx & 63] = Wk[idx];
    }
    const int R0 = blockIdx.x * 16;
    const float* src; half_t* dqf; half_t* dkf; int r0;
    if (R0 < N) { src = X; dqf = Qfx; dkf = Kfx; r0 = R0; }
    else        { src = Y; dqf = Qfy; dkf = Kfy; r0 = R0 - N; }
#pragma unroll
    for (int p = 0; p < 4; ++p) {
        int idx = p * 256 + t;
        sIn[idx >> 6][idx & 63] = src[(size_t)r0 * D + idx];
    }
    __syncthreads();
    const int c = t & 63;
    const int rb = t >> 6;
    const int ksi = c >> 5, quadi = (c >> 3) & 3, j = c & 7;
#pragma unroll
    for (int rr = 0; rr < 4; ++rr) {
        int r = rr * 4 + rb;
        float aq = 0.f, ak = 0.f;
#pragma unroll
        for (int k = 0; k < 64; ++k) {
            float xv = sIn[r][k];
            aq = fmaf(xv, sWq[k][c], aq);
            ak = fmaf(xv, sWk[k][c], ak);
        }
        aq *= (0.125f * LOG2E);
        int rg = r0 + r;
        int tile = rg >> 5, tau = (rg >> 4) & 1, c16l = rg & 15;
        size_t idx = (size_t)tile * 4096 + ksi * 2048 + tau * 1024
                   + (quadi * 16 + c16l) * 8 + j;
        half_t qhh = (half_t)aq;
        dqf[idx]       = qhh;
        dqf[idx + 512] = (half_t)(aq - (float)qhh);
        half_t khh = (half_t)ak;
        dkf[idx]       = khh;
        dkf[idx + 512] = (half_t)(ak - (float)khh);
    }
}

// ---------------------------------------------------------------------------
// K2: Zf prep (transposed input, f16 HI only, frag-major). grid (N/32, 2).
// ---------------------------------------------------------------------------
__global__ __launch_bounds__(256) void ztprep_kernel(
    const float* __restrict__ X, const float* __restrict__ Y,
    half_t* __restrict__ Zfx, half_t* __restrict__ Zfy)
{
    const int t = threadIdx.x;
    const int tile = blockIdx.x;
    const float* src = blockIdx.y ? Y : X;
    half_t* dst = blockIdx.y ? Zfy : Zfx;
    const int dt = t >> 6, lane = t & 63;
    const int quad = lane >> 4, c16 = lane & 15;
    f16x8 h;
#pragma unroll
    for (int j = 0; j < 8; ++j)
        h[j] = (half_t)src[(size_t)(tile * 32 + quad * 8 + j) * D + dt * 16 + c16];
    *(f16x8*)&dst[(size_t)tile * 2048 + dt * 512 + lane * 8] = h;
}

// ---------------------------------------------------------------------------
// K3: flash attention — R4 version (R0 structure + s_setprio around MFMA
// clusters). 4-wave 256-thread blocks, 2/CU, register ping-pong K prefetch,
// zero barriers. Measured 83 us (R5). Numerics bit-identical to R0.
// ---------------------------------------------------------------------------
__global__ __launch_bounds__(256, 2) void attn_kernel(
    const half_t* __restrict__ Qfx, const half_t* __restrict__ Qfy,
    const half_t* __restrict__ Kfx, const half_t* __restrict__ Kfy,
    const half_t* __restrict__ Zfx, const half_t* __restrict__ Zfy,
    half_t* __restrict__ Opart, float* __restrict__ mpart, float* __restrict__ lpart)
{
    const int side = blockIdx.y;
    const half_t* Qf = side ? Qfy : Qfx;
    const half_t* Kf = side ? Kfy : Kfx;
    const half_t* Zf = side ? Zfy : Zfx;
    const int t = threadIdx.x, w = t >> 6, lane = t & 63;
    const int c16 = lane & 15, quad = lane >> 4;
    const int q0 = blockIdx.x * 128 + w * 32;
    const int tile0 = blockIdx.z * (N / KS / 32);
    const int ITERS = (N / KS) / 32;   // 64

    __shared__ half_t Pbuf[4][32][40];   // [wave][q][kv(+pad)] hi only
    half_t (*Phi)[40] = Pbuf[w];

    f16x8 qh[2][2], ql[2][2];   // [qg][ks]
    {
        const half_t* qb = Qf + (size_t)(q0 >> 5) * 4096 + lane * 8;
#pragma unroll
        for (int ks = 0; ks < 2; ++ks)
#pragma unroll
            for (int qg = 0; qg < 2; ++qg) {
                qh[qg][ks] = *(const f16x8*)&qb[ks * 2048 + qg * 1024];
                ql[qg][ks] = *(const f16x8*)&qb[ks * 2048 + qg * 1024 + 512];
            }
    }

    f32x4 ot[4][2] = {};      // O^T accumulators [dt][qg]
    f32x4 lacc[2] = {};       // l accumulators via ones-row MFMA
    float m_run[2] = {-INFINITY, -INFINITY};
    f16x8 ones;
#pragma unroll
    for (int i = 0; i < 8; ++i) ones[i] = (half_t)1.0f;

    f16x8 kAh[2][2], kAl[2][2], kBh[2][2], kBl[2][2];   // ping-pong K frags
    f32x4 stA[2][2], stB[2][2];                          // double-buffered S^T

    auto loadK = [&](int tile, f16x8 (&kh)[2][2], f16x8 (&kl)[2][2]) {
        const half_t* b = Kf + (size_t)tile * 4096 + lane * 8;
#pragma unroll
        for (int ks = 0; ks < 2; ++ks)
#pragma unroll
            for (int tau = 0; tau < 2; ++tau) {
                kh[ks][tau] = *(const f16x8*)&b[ks * 2048 + tau * 1024];
                kl[ks][tau] = *(const f16x8*)&b[ks * 2048 + tau * 1024 + 512];
            }
    };
    auto doS = [&](f32x4 (&st)[2][2], f16x8 (&kh)[2][2], f16x8 (&kl)[2][2]) {
        const f32x4 zero = {};
#pragma unroll
        for (int qg = 0; qg < 2; ++qg)
#pragma unroll
            for (int tau = 0; tau < 2; ++tau) st[qg][tau] = zero;
        __builtin_amdgcn_s_setprio(1);
#pragma unroll
        for (int ks = 0; ks < 2; ++ks)
#pragma unroll
            for (int tau = 0; tau < 2; ++tau)
#pragma unroll
                for (int qg = 0; qg < 2; ++qg) {
                    st[qg][tau] = MFMA32(kh[ks][tau], qh[qg][ks], st[qg][tau]);
                    st[qg][tau] = MFMA32(kh[ks][tau], ql[qg][ks], st[qg][tau]);
                    st[qg][tau] = MFMA32(kl[ks][tau], qh[qg][ks], st[qg][tau]);
                }
        __builtin_amdgcn_s_setprio(0);
    };

    auto body = [&](int tt, f32x4 (&stCur)[2][2], f32x4 (&stNext)[2][2],
                    f16x8 (&kNh)[2][2], f16x8 (&kNl)[2][2],
                    f16x8 (&kRh)[2][2], f16x8 (&kRl)[2][2]) {
        if (tt + 1 < ITERS) doS(stNext, kNh, kNl);           // S(t+1) in background
        if (tt + 2 < ITERS) loadK(tile0 + tt + 2, kRh, kRl); // K(t+2) in flight
        const half_t* zb = Zf + (size_t)(tile0 + tt) * 2048 + lane * 8;
        f16x8 zh[4];
#pragma unroll
        for (int dt = 0; dt < 4; ++dt)
            zh[dt] = *(const f16x8*)&zb[dt * 512];
        // ---- online softmax (exp2 domain), P hi-only ----
#pragma unroll
        for (int qg = 0; qg < 2; ++qg) {
            float mt = fmaxf(fmaxf(fmaxf(stCur[qg][0][0], stCur[qg][0][1]),
                                   fmaxf(stCur[qg][0][2], stCur[qg][0][3])),
                             fmaxf(fmaxf(stCur[qg][1][0], stCur[qg][1][1]),
                                   fmaxf(stCur[qg][1][2], stCur[qg][1][3])));
            mt = fmaxf(mt, __shfl_xor(mt, 16));
            mt = fmaxf(mt, __shfl_xor(mt, 32));
            float mn = fmaxf(m_run[qg], mt);
            float al = exp2f(m_run[qg] - mn);
            m_run[qg] = mn;
#pragma unroll
            for (int tau = 0; tau < 2; ++tau) {
                f16x4 h4;
#pragma unroll
                for (int r = 0; r < 4; ++r)
                    h4[r] = (half_t)exp2f(stCur[qg][tau][r] - mn);
                *(f16x4*)&Phi[16 * qg + c16][16 * tau + 4 * quad] = h4;
            }
            lacc[qg] *= al;
#pragma unroll
            for (int dt = 0; dt < 4; ++dt) ot[dt][qg] *= al;
        }
        // ---- P B-frags from LDS, PV + l ----
        f16x8 pbh[2];
#pragma unroll
        for (int qg = 0; qg < 2; ++qg)
            pbh[qg] = *(const f16x8*)&Phi[16 * qg + c16][quad * 8];
        __builtin_amdgcn_s_setprio(1);
#pragma unroll
        for (int dt = 0; dt < 4; ++dt)
#pragma unroll
            for (int qg = 0; qg < 2; ++qg)
                ot[dt][qg] = MFMA32(zh[dt], pbh[qg], ot[dt][qg]);
#pragma unroll
        for (int qg = 0; qg < 2; ++qg)
            lacc[qg] = MFMA32(ones, pbh[qg], lacc[qg]);
        __builtin_amdgcn_s_setprio(0);
    };

    loadK(tile0, kAh, kAl);
    doS(stA, kAh, kAl);                         // S(0)
    if (ITERS > 1) loadK(tile0 + 1, kBh, kBl);  // K(1)
#pragma unroll 1
    for (int tt = 0; tt < ITERS; tt += 2) {
        body(tt,     stA, stB, kBh, kBl, kAh, kAl);
        body(tt + 1, stB, stA, kAh, kAl, kBh, kBl);
    }

    // epilogue: unnormalized O (f16, relative to m_run) + m, l partials (f32)
    const size_t obase = (size_t)(side * KS + blockIdx.z) * N;
#pragma unroll
    for (int qg = 0; qg < 2; ++qg) {
        int q = q0 + 16 * qg + c16;
#pragma unroll
        for (int dt = 0; dt < 4; ++dt) {
            f16x4 o4;
#pragma unroll
            for (int r = 0; r < 4; ++r) o4[r] = (half_t)ot[dt][qg][r];
            *(f16x4*)&Opart[(obase + q) * D + 16 * dt + 4 * quad] = o4;
        }
        if (quad == 0) {
            mpart[obase + q] = m_run[qg];
            lpart[obase + q] = lacc[qg][0];
        }
    }
}

// ---------------------------------------------------------------------------
// K4: combine split-K partials (f16) -> Xf/Yf f16 HI-only frag-major.
// ---------------------------------------------------------------------------
__global__ __launch_bounds__(256) void combine_kernel(
    const half_t* __restrict__ Opart, const float* __restrict__ mpart,
    const float* __restrict__ lpart,
    half_t* __restrict__ Xf, half_t* __restrict__ Yf,
    float* __restrict__ n2x, float* __restrict__ n2y)
{
    const int side = blockIdx.y;
    const int q = blockIdx.x * 16 + (threadIdx.x >> 4);
    const int d4 = (threadIdx.x & 15) * 4;
    float m[KS], l[KS];
#pragma unroll
    for (int s = 0; s < KS; ++s) {
        size_t b = (size_t)(side * KS + s) * N + q;
        m[s] = mpart[b]; l[s] = lpart[b];
    }
    float M = -INFINITY;
#pragma unroll
    for (int s = 0; s < KS; ++s) M = fmaxf(M, m[s]);
    float L = 0.f;
    f32x4 o = {0.f, 0.f, 0.f, 0.f};
#pragma unroll
    for (int s = 0; s < KS; ++s) {
        float sc = exp2f(m[s] - M);
        L += l[s] * sc;
        f16x4 p4 = *(const f16x4*)&Opart[((size_t)(side * KS + s) * N + q) * D + d4];
#pragma unroll
        for (int i = 0; i < 4; ++i) o[i] = fmaf((float)p4[i], sc, o[i]);
    }
    const float oscale = (side ? 1.0f : 2.0f * LOG2E) / L;
    f16x4 h4;
#pragma unroll
    for (int i = 0; i < 4; ++i) h4[i] = (half_t)(o[i] * oscale);
    float sq = 0.f;
#pragma unroll
    for (int i = 0; i < 4; ++i) { float hv = (float)h4[i]; sq = fmaf(hv, hv, sq); }
#pragma unroll
    for (int off = 1; off < 16; off <<= 1) sq += __shfl_xor(sq, off);
    half_t* dst = side ? Yf : Xf;
    float*  n2  = side ? n2y : n2x;
    if ((threadIdx.x & 15) == 0)
        n2[q] = side ? sq * LOG2E : sq * (0.25f / LOG2E);
    const int tile16 = q >> 4, c16l = q & 15;
    const int ksi = d4 >> 5, quadi = (d4 >> 3) & 3, j0 = d4 & 7;
    *(f16x4*)&dst[(size_t)tile16 * 1024 + ksi * 512 + (quadi * 16 + c16l) * 8 + j0] = h4;
}

// ---------------------------------------------------------------------------
// K5: RBF via single-term f16 MFMA (consistent-points numerics), frag-major
// loads. EXACT R0 version (A=X frag, B=Y frag, scalar stores).
// ---------------------------------------------------------------------------
__global__ __launch_bounds__(256, 4) void rbf_kernel(
    const half_t* __restrict__ Xf, const half_t* __restrict__ Yf,
    const float* __restrict__ n2x, const float* __restrict__ n2y,
    float* __restrict__ out)
{
    const int t = threadIdx.x, w = t >> 6, lane = t & 63;
    const int c16 = lane & 15, quad = lane >> 4;
    const int X0 = blockIdx.y * 128 + (w >> 1) * 64;
    const int Y0 = blockIdx.x * 128 + (w & 1) * 64;
    float ny[4];
    f32x4 nx4[4];
#pragma unroll
    for (int yt = 0; yt < 4; ++yt) ny[yt] = n2y[Y0 + 16 * yt + c16];
#pragma unroll
    for (int xt = 0; xt < 4; ++xt)
        nx4[xt] = *(const f32x4*)&n2x[X0 + 16 * xt + 4 * quad];

    const half_t* Xb = Xf + lane * 8;
    const half_t* Yb = Yf + lane * 8;
    f32x4 acc[4][4] = {};   // [xt][yt]
#pragma unroll
    for (int ks = 0; ks < 2; ++ks) {
        f16x8 bh[4];
#pragma unroll
        for (int yt = 0; yt < 4; ++yt)
            bh[yt] = *(const f16x8*)&Yb[(size_t)((Y0 >> 4) + yt) * 1024 + ks * 512];
#pragma unroll
        for (int xt = 0; xt < 4; ++xt) {
            f16x8 ah = *(const f16x8*)&Xb[(size_t)((X0 >> 4) + xt) * 1024 + ks * 512];
#pragma unroll
            for (int yt = 0; yt < 4; ++yt)
                acc[xt][yt] = MFMA32(ah, bh[yt], acc[xt][yt]);
        }
    }
#pragma unroll
    for (int xt = 0; xt < 4; ++xt)
#pragma unroll
        for (int r = 0; r < 4; ++r) {
            int xr = X0 + 16 * xt + 4 * quad + r;
            float nx = nx4[xt][r];
#pragma unroll
            for (int yt = 0; yt < 4; ++yt) {
                float v = exp2f(acc[xt][yt][r] - nx - ny[yt]);
                out[(size_t)xr * N + Y0 + 16 * yt + c16] = v;
            }
        }
}

// ---------------------------------------------------------------------------
extern "C" void kernel_launch(void* const* d_in, const int* in_sizes, int n_in,
                              void* d_out, int out_size, void* d_ws, size_t ws_size,
                              hipStream_t stream) {
    const float* Wq = (const float*)d_in[0];
    const float* Wk = (const float*)d_in[1];
    const float* x  = (const float*)d_in[2];
    const float* y  = (const float*)d_in[3];
    float* out = (float*)d_out;

    char* p = (char*)d_ws;
    size_t used = 0;
    auto alloc = [&](size_t bytes) -> void* {
        void* r = (void*)(p + used);
        used += (bytes + 255) & ~(size_t)255;
        return r;
    };
    half_t* Qfx = (half_t*)alloc((size_t)N * D * 2 * 2);   // hi+lo frag-major
    half_t* Qfy = (half_t*)alloc((size_t)N * D * 2 * 2);
    half_t* Kfx = (half_t*)alloc((size_t)N * D * 2 * 2);
    half_t* Kfy = (half_t*)alloc((size_t)N * D * 2 * 2);
    half_t* Zfx = (half_t*)alloc((size_t)N * D * 2);       // hi only
    half_t* Zfy = (half_t*)alloc((size_t)N * D * 2);
    half_t* Xf  = (half_t*)alloc((size_t)N * D * 2);       // hi only
    half_t* Yf  = (half_t*)alloc((size_t)N * D * 2);
    float*  n2x = (float*) alloc((size_t)N * 4);
    float*  n2y = (float*) alloc((size_t)N * 4);
    half_t* Opart = (half_t*)alloc((size_t)2 * KS * N * D * 2);   // f16 partials
    float*  mpart = (float*) alloc((size_t)2 * KS * N * 4);
    float*  lpart = (float*) alloc((size_t)2 * KS * N * 4);

    proj_kernel<<<dim3(2 * N / 16), 256, 0, stream>>>(Wq, Wk, x, y,
                                                      Qfx, Qfy, Kfx, Kfy);
    ztprep_kernel<<<dim3(N / 32, 2), 256, 0, stream>>>(x, y, Zfx, Zfy);
    attn_kernel<<<dim3(N / 128, 2, KS), 256, 0, stream>>>(
        Qfx, Qfy, Kfx, Kfy, Zfx, Zfy, Opart, mpart, lpart);
    combine_kernel<<<dim3(N / 16, 2), 256, 0, stream>>>(
        Opart, mpart, lpart, Xf, Yf, n2x, n2y);
    // MEASUREMENT: rbf launched twice. Second run rewrites identical values
    // (same inputs -> same outputs), so result is bit-identical to R4.
    // rbf_time = dur_us(this round) - 386.2 (R4).
    rbf_kernel<<<dim3(N / 128, N / 128), 256, 0, stream>>>(Xf, Yf, n2x, n2y, out);
    rbf_kernel<<<dim3(N / 128, N / 128), 256, 0, stream>>>(Xf, Yf, n2x, n2y, out);
}

// Round 7
// 390.129 us; speedup vs baseline: 1.2031x; 1.0806x over previous
//
#include <hip/hip_runtime.h>
#include <math.h>

#define N 8192
#define D 64
#define KS 4
#define LOG2E 1.4426950408889634f

typedef _Float16 half_t;
typedef _Float16 f16x8 __attribute__((ext_vector_type(8)));
typedef _Float16 f16x4 __attribute__((ext_vector_type(4)));
typedef float f32x4 __attribute__((ext_vector_type(4)));

#define MFMA32(a, b, c) __builtin_amdgcn_mfma_f32_16x16x32_f16((a), (b), (c), 0, 0, 0)

// Fragment-major layouts (hot-loop loads are base + lane*16B):
//  Qf,Kf [tile32][ks][tau][hl][lane][8] : elem (row=tile*32+tau*16+c16, col=ks*32+quad*8+j)
//  Zf    [tile32][dt][lane][8]          : elem (row=tile*32+quad*8+j, d=dt*16+c16)  HI only
//  XYf   [tile16][ks][lane][8]          : elem (row=tile*16+c16, col=ks*32+quad*8+j) HI only
// where lane = quad*16 + c16.
//
// Session ledger (measured): R4=386.2 best. attn=83 (R5 dup-launch), rbf=35
// (R6 dup-launch), fills+fixed overhead ~254 of dur_us. R7: attn load-issue
// hoists only (order-only, bit-identical); rbf back to single launch.

// ---------------------------------------------------------------------------
// K1: Qf = (X@Wq)*0.125*log2e, Kf = X@Wk, both f16 hi/lo frag-major.
// (EXACT R0 version — rr-outer.)
// ---------------------------------------------------------------------------
__global__ __launch_bounds__(256) void proj_kernel(
    const float* __restrict__ Wq, const float* __restrict__ Wk,
    const float* __restrict__ X, const float* __restrict__ Y,
    half_t* __restrict__ Qfx, half_t* __restrict__ Qfy,
    half_t* __restrict__ Kfx, half_t* __restrict__ Kfy)
{
    __shared__ float sWq[64][64];
    __shared__ float sWk[64][64];
    __shared__ float sIn[16][64];
    const int t = threadIdx.x;
#pragma unroll
    for (int p = 0; p < 16; ++p) {
        int idx = p * 256 + t;
        sWq[idx >> 6][idx & 63] = Wq[idx];
        sWk[idx >> 6][idx & 63] = Wk[idx];
    }
    const int R0 = blockIdx.x * 16;
    const float* src; half_t* dqf; half_t* dkf; int r0;
    if (R0 < N) { src = X; dqf = Qfx; dkf = Kfx; r0 = R0; }
    else        { src = Y; dqf = Qfy; dkf = Kfy; r0 = R0 - N; }
#pragma unroll
    for (int p = 0; p < 4; ++p) {
        int idx = p * 256 + t;
        sIn[idx >> 6][idx & 63] = src[(size_t)r0 * D + idx];
    }
    __syncthreads();
    const int c = t & 63;
    const int rb = t >> 6;
    const int ksi = c >> 5, quadi = (c >> 3) & 3, j = c & 7;
#pragma unroll
    for (int rr = 0; rr < 4; ++rr) {
        int r = rr * 4 + rb;
        float aq = 0.f, ak = 0.f;
#pragma unroll
        for (int k = 0; k < 64; ++k) {
            float xv = sIn[r][k];
            aq = fmaf(xv, sWq[k][c], aq);
            ak = fmaf(xv, sWk[k][c], ak);
        }
        aq *= (0.125f * LOG2E);
        int rg = r0 + r;
        int tile = rg >> 5, tau = (rg >> 4) & 1, c16l = rg & 15;
        size_t idx = (size_t)tile * 4096 + ksi * 2048 + tau * 1024
                   + (quadi * 16 + c16l) * 8 + j;
        half_t qhh = (half_t)aq;
        dqf[idx]       = qhh;
        dqf[idx + 512] = (half_t)(aq - (float)qhh);
        half_t khh = (half_t)ak;
        dkf[idx]       = khh;
        dkf[idx + 512] = (half_t)(ak - (float)khh);
    }
}

// ---------------------------------------------------------------------------
// K2: Zf prep (transposed input, f16 HI only, frag-major). grid (N/32, 2).
// ---------------------------------------------------------------------------
__global__ __launch_bounds__(256) void ztprep_kernel(
    const float* __restrict__ X, const float* __restrict__ Y,
    half_t* __restrict__ Zfx, half_t* __restrict__ Zfy)
{
    const int t = threadIdx.x;
    const int tile = blockIdx.x;
    const float* src = blockIdx.y ? Y : X;
    half_t* dst = blockIdx.y ? Zfy : Zfx;
    const int dt = t >> 6, lane = t & 63;
    const int quad = lane >> 4, c16 = lane & 15;
    f16x8 h;
#pragma unroll
    for (int j = 0; j < 8; ++j)
        h[j] = (half_t)src[(size_t)(tile * 32 + quad * 8 + j) * D + dt * 16 + c16];
    *(f16x8*)&dst[(size_t)tile * 2048 + dt * 512 + lane * 8] = h;
}

// ---------------------------------------------------------------------------
// K3: flash attention — R4 structure (4-wave 256-thread blocks, 2/CU,
// register ping-pong K prefetch, zero barriers, setprio on MFMA clusters).
// R7 delta (order-only, bit-identical): (a) Z(t) loads issued at TOP of body
// (gains the doS issue window of flight time before PV reads them);
// (b) loadK(t+2) issued BEFORE doS(stNext) (destination regs were freed one
// body earlier — pure reorder). No register-count or numerics change.
// ---------------------------------------------------------------------------
__global__ __launch_bounds__(256, 2) void attn_kernel(
    const half_t* __restrict__ Qfx, const half_t* __restrict__ Qfy,
    const half_t* __restrict__ Kfx, const half_t* __restrict__ Kfy,
    const half_t* __restrict__ Zfx, const half_t* __restrict__ Zfy,
    half_t* __restrict__ Opart, float* __restrict__ mpart, float* __restrict__ lpart)
{
    const int side = blockIdx.y;
    const half_t* Qf = side ? Qfy : Qfx;
    const half_t* Kf = side ? Kfy : Kfx;
    const half_t* Zf = side ? Zfy : Zfx;
    const int t = threadIdx.x, w = t >> 6, lane = t & 63;
    const int c16 = lane & 15, quad = lane >> 4;
    const int q0 = blockIdx.x * 128 + w * 32;
    const int tile0 = blockIdx.z * (N / KS / 32);
    const int ITERS = (N / KS) / 32;   // 64

    __shared__ half_t Pbuf[4][32][40];   // [wave][q][kv(+pad)] hi only
    half_t (*Phi)[40] = Pbuf[w];

    f16x8 qh[2][2], ql[2][2];   // [qg][ks]
    {
        const half_t* qb = Qf + (size_t)(q0 >> 5) * 4096 + lane * 8;
#pragma unroll
        for (int ks = 0; ks < 2; ++ks)
#pragma unroll
            for (int qg = 0; qg < 2; ++qg) {
                qh[qg][ks] = *(const f16x8*)&qb[ks * 2048 + qg * 1024];
                ql[qg][ks] = *(const f16x8*)&qb[ks * 2048 + qg * 1024 + 512];
            }
    }

    f32x4 ot[4][2] = {};      // O^T accumulators [dt][qg]
    f32x4 lacc[2] = {};       // l accumulators via ones-row MFMA
    float m_run[2] = {-INFINITY, -INFINITY};
    f16x8 ones;
#pragma unroll
    for (int i = 0; i < 8; ++i) ones[i] = (half_t)1.0f;

    f16x8 kAh[2][2], kAl[2][2], kBh[2][2], kBl[2][2];   // ping-pong K frags
    f32x4 stA[2][2], stB[2][2];                          // double-buffered S^T

    auto loadK = [&](int tile, f16x8 (&kh)[2][2], f16x8 (&kl)[2][2]) {
        const half_t* b = Kf + (size_t)tile * 4096 + lane * 8;
#pragma unroll
        for (int ks = 0; ks < 2; ++ks)
#pragma unroll
            for (int tau = 0; tau < 2; ++tau) {
                kh[ks][tau] = *(const f16x8*)&b[ks * 2048 + tau * 1024];
                kl[ks][tau] = *(const f16x8*)&b[ks * 2048 + tau * 1024 + 512];
            }
    };
    auto doS = [&](f32x4 (&st)[2][2], f16x8 (&kh)[2][2], f16x8 (&kl)[2][2]) {
        const f32x4 zero = {};
#pragma unroll
        for (int qg = 0; qg < 2; ++qg)
#pragma unroll
            for (int tau = 0; tau < 2; ++tau) st[qg][tau] = zero;
        __builtin_amdgcn_s_setprio(1);
#pragma unroll
        for (int ks = 0; ks < 2; ++ks)
#pragma unroll
            for (int tau = 0; tau < 2; ++tau)
#pragma unroll
                for (int qg = 0; qg < 2; ++qg) {
                    st[qg][tau] = MFMA32(kh[ks][tau], qh[qg][ks], st[qg][tau]);
                    st[qg][tau] = MFMA32(kh[ks][tau], ql[qg][ks], st[qg][tau]);
                    st[qg][tau] = MFMA32(kl[ks][tau], qh[qg][ks], st[qg][tau]);
                }
        __builtin_amdgcn_s_setprio(0);
    };

    auto body = [&](int tt, f32x4 (&stCur)[2][2], f32x4 (&stNext)[2][2],
                    f16x8 (&kNh)[2][2], f16x8 (&kNl)[2][2],
                    f16x8 (&kRh)[2][2], f16x8 (&kRl)[2][2]) {
        // R7: issue Z(t) loads FIRST — flight time spans doS + softmax.
        const half_t* zb = Zf + (size_t)(tile0 + tt) * 2048 + lane * 8;
        f16x8 zh[4];
#pragma unroll
        for (int dt = 0; dt < 4; ++dt)
            zh[dt] = *(const f16x8*)&zb[dt * 512];
        // R7: issue K(t+2) loads before the MFMA cluster (regs freed last body).
        if (tt + 2 < ITERS) loadK(tile0 + tt + 2, kRh, kRl);
        if (tt + 1 < ITERS) doS(stNext, kNh, kNl);           // S(t+1) in background
        // ---- online softmax (exp2 domain), P hi-only ----
#pragma unroll
        for (int qg = 0; qg < 2; ++qg) {
            float mt = fmaxf(fmaxf(fmaxf(stCur[qg][0][0], stCur[qg][0][1]),
                                   fmaxf(stCur[qg][0][2], stCur[qg][0][3])),
                             fmaxf(fmaxf(stCur[qg][1][0], stCur[qg][1][1]),
                                   fmaxf(stCur[qg][1][2], stCur[qg][1][3])));
            mt = fmaxf(mt, __shfl_xor(mt, 16));
            mt = fmaxf(mt, __shfl_xor(mt, 32));
            float mn = fmaxf(m_run[qg], mt);
            float al = exp2f(m_run[qg] - mn);
            m_run[qg] = mn;
#pragma unroll
            for (int tau = 0; tau < 2; ++tau) {
                f16x4 h4;
#pragma unroll
                for (int r = 0; r < 4; ++r)
                    h4[r] = (half_t)exp2f(stCur[qg][tau][r] - mn);
                *(f16x4*)&Phi[16 * qg + c16][16 * tau + 4 * quad] = h4;
            }
            lacc[qg] *= al;
#pragma unroll
            for (int dt = 0; dt < 4; ++dt) ot[dt][qg] *= al;
        }
        // ---- P B-frags from LDS, PV + l ----
        f16x8 pbh[2];
#pragma unroll
        for (int qg = 0; qg < 2; ++qg)
            pbh[qg] = *(const f16x8*)&Phi[16 * qg + c16][quad * 8];
        __builtin_amdgcn_s_setprio(1);
#pragma unroll
        for (int dt = 0; dt < 4; ++dt)
#pragma unroll
            for (int qg = 0; qg < 2; ++qg)
                ot[dt][qg] = MFMA32(zh[dt], pbh[qg], ot[dt][qg]);
#pragma unroll
        for (int qg = 0; qg < 2; ++qg)
            lacc[qg] = MFMA32(ones, pbh[qg], lacc[qg]);
        __builtin_amdgcn_s_setprio(0);
    };

    loadK(tile0, kAh, kAl);
    doS(stA, kAh, kAl);                         // S(0)
    if (ITERS > 1) loadK(tile0 + 1, kBh, kBl);  // K(1)
#pragma unroll 1
    for (int tt = 0; tt < ITERS; tt += 2) {
        body(tt,     stA, stB, kBh, kBl, kAh, kAl);
        body(tt + 1, stB, stA, kAh, kAl, kBh, kBl);
    }

    // epilogue: unnormalized O (f16, relative to m_run) + m, l partials (f32)
    const size_t obase = (size_t)(side * KS + blockIdx.z) * N;
#pragma unroll
    for (int qg = 0; qg < 2; ++qg) {
        int q = q0 + 16 * qg + c16;
#pragma unroll
        for (int dt = 0; dt < 4; ++dt) {
            f16x4 o4;
#pragma unroll
            for (int r = 0; r < 4; ++r) o4[r] = (half_t)ot[dt][qg][r];
            *(f16x4*)&Opart[(obase + q) * D + 16 * dt + 4 * quad] = o4;
        }
        if (quad == 0) {
            mpart[obase + q] = m_run[qg];
            lpart[obase + q] = lacc[qg][0];
        }
    }
}

// ---------------------------------------------------------------------------
// K4: combine split-K partials (f16) -> Xf/Yf f16 HI-only frag-major.
// ---------------------------------------------------------------------------
__global__ __launch_bounds__(256) void combine_kernel(
    const half_t* __restrict__ Opart, const float* __restrict__ mpart,
    const float* __restrict__ lpart,
    half_t* __restrict__ Xf, half_t* __restrict__ Yf,
    float* __restrict__ n2x, float* __restrict__ n2y)
{
    const int side = blockIdx.y;
    const int q = blockIdx.x * 16 + (threadIdx.x >> 4);
    const int d4 = (threadIdx.x & 15) * 4;
    float m[KS], l[KS];
#pragma unroll
    for (int s = 0; s < KS; ++s) {
        size_t b = (size_t)(side * KS + s) * N + q;
        m[s] = mpart[b]; l[s] = lpart[b];
    }
    float M = -INFINITY;
#pragma unroll
    for (int s = 0; s < KS; ++s) M = fmaxf(M, m[s]);
    float L = 0.f;
    f32x4 o = {0.f, 0.f, 0.f, 0.f};
#pragma unroll
    for (int s = 0; s < KS; ++s) {
        float sc = exp2f(m[s] - M);
        L += l[s] * sc;
        f16x4 p4 = *(const f16x4*)&Opart[((size_t)(side * KS + s) * N + q) * D + d4];
#pragma unroll
        for (int i = 0; i < 4; ++i) o[i] = fmaf((float)p4[i], sc, o[i]);
    }
    const float oscale = (side ? 1.0f : 2.0f * LOG2E) / L;
    f16x4 h4;
#pragma unroll
    for (int i = 0; i < 4; ++i) h4[i] = (half_t)(o[i] * oscale);
    float sq = 0.f;
#pragma unroll
    for (int i = 0; i < 4; ++i) { float hv = (float)h4[i]; sq = fmaf(hv, hv, sq); }
#pragma unroll
    for (int off = 1; off < 16; off <<= 1) sq += __shfl_xor(sq, off);
    half_t* dst = side ? Yf : Xf;
    float*  n2  = side ? n2y : n2x;
    if ((threadIdx.x & 15) == 0)
        n2[q] = side ? sq * LOG2E : sq * (0.25f / LOG2E);
    const int tile16 = q >> 4, c16l = q & 15;
    const int ksi = d4 >> 5, quadi = (d4 >> 3) & 3, j0 = d4 & 7;
    *(f16x4*)&dst[(size_t)tile16 * 1024 + ksi * 512 + (quadi * 16 + c16l) * 8 + j0] = h4;
}

// ---------------------------------------------------------------------------
// K5: RBF via single-term f16 MFMA (consistent-points numerics), frag-major
// loads. EXACT R0 version (A=X frag, B=Y frag, scalar stores). Measured
// ~35us (R6) — at its 268MB write floor; done.
// ---------------------------------------------------------------------------
__global__ __launch_bounds__(256, 4) void rbf_kernel(
    const half_t* __restrict__ Xf, const half_t* __restrict__ Yf,
    const float* __restrict__ n2x, const float* __restrict__ n2y,
    float* __restrict__ out)
{
    const int t = threadIdx.x, w = t >> 6, lane = t & 63;
    const int c16 = lane & 15, quad = lane >> 4;
    const int X0 = blockIdx.y * 128 + (w >> 1) * 64;
    const int Y0 = blockIdx.x * 128 + (w & 1) * 64;
    float ny[4];
    f32x4 nx4[4];
#pragma unroll
    for (int yt = 0; yt < 4; ++yt) ny[yt] = n2y[Y0 + 16 * yt + c16];
#pragma unroll
    for (int xt = 0; xt < 4; ++xt)
        nx4[xt] = *(const f32x4*)&n2x[X0 + 16 * xt + 4 * quad];

    const half_t* Xb = Xf + lane * 8;
    const half_t* Yb = Yf + lane * 8;
    f32x4 acc[4][4] = {};   // [xt][yt]
#pragma unroll
    for (int ks = 0; ks < 2; ++ks) {
        f16x8 bh[4];
#pragma unroll
        for (int yt = 0; yt < 4; ++yt)
            bh[yt] = *(const f16x8*)&Yb[(size_t)((Y0 >> 4) + yt) * 1024 + ks * 512];
#pragma unroll
        for (int xt = 0; xt < 4; ++xt) {
            f16x8 ah = *(const f16x8*)&Xb[(size_t)((X0 >> 4) + xt) * 1024 + ks * 512];
#pragma unroll
            for (int yt = 0; yt < 4; ++yt)
                acc[xt][yt] = MFMA32(ah, bh[yt], acc[xt][yt]);
        }
    }
#pragma unroll
    for (int xt = 0; xt < 4; ++xt)
#pragma unroll
        for (int r = 0; r < 4; ++r) {
            int xr = X0 + 16 * xt + 4 * quad + r;
            float nx = nx4[xt][r];
#pragma unroll
            for (int yt = 0; yt < 4; ++yt) {
                float v = exp2f(acc[xt][yt][r] - nx - ny[yt]);
                out[(size_t)xr * N + Y0 + 16 * yt + c16] = v;
            }
        }
}

// ---------------------------------------------------------------------------
extern "C" void kernel_launch(void* const* d_in, const int* in_sizes, int n_in,
                              void* d_out, int out_size, void* d_ws, size_t ws_size,
                              hipStream_t stream) {
    const float* Wq = (const float*)d_in[0];
    const float* Wk = (const float*)d_in[1];
    const float* x  = (const float*)d_in[2];
    const float* y  = (const float*)d_in[3];
    float* out = (float*)d_out;

    char* p = (char*)d_ws;
    size_t used = 0;
    auto alloc = [&](size_t bytes) -> void* {
        void* r = (void*)(p + used);
        used += (bytes + 255) & ~(size_t)255;
        return r;
    };
    half_t* Qfx = (half_t*)alloc((size_t)N * D * 2 * 2);   // hi+lo frag-major
    half_t* Qfy = (half_t*)alloc((size_t)N * D * 2 * 2);
    half_t* Kfx = (half_t*)alloc((size_t)N * D * 2 * 2);
    half_t* Kfy = (half_t*)alloc((size_t)N * D * 2 * 2);
    half_t* Zfx = (half_t*)alloc((size_t)N * D * 2);       // hi only
    half_t* Zfy = (half_t*)alloc((size_t)N * D * 2);
    half_t* Xf  = (half_t*)alloc((size_t)N * D * 2);       // hi only
    half_t* Yf  = (half_t*)alloc((size_t)N * D * 2);
    float*  n2x = (float*) alloc((size_t)N * 4);
    float*  n2y = (float*) alloc((size_t)N * 4);
    half_t* Opart = (half_t*)alloc((size_t)2 * KS * N * D * 2);   // f16 partials
    float*  mpart = (float*) alloc((size_t)2 * KS * N * 4);
    float*  lpart = (float*) alloc((size_t)2 * KS * N * 4);

    proj_kernel<<<dim3(2 * N / 16), 256, 0, stream>>>(Wq, Wk, x, y,
                                                      Qfx, Qfy, Kfx, Kfy);
    ztprep_kernel<<<dim3(N / 32, 2), 256, 0, stream>>>(x, y, Zfx, Zfy);
    attn_kernel<<<dim3(N / 128, 2, KS), 256, 0, stream>>>(
        Qfx, Qfy, Kfx, Kfy, Zfx, Zfy, Opart, mpart, lpart);
    combine_kernel<<<dim3(N / 16, 2), 256, 0, stream>>>(
        Opart, mpart, lpart, Xf, Yf, n2x, n2y);
    rbf_kernel<<<dim3(N / 128, N / 128), 256, 0, stream>>>(Xf, Yf, n2x, n2y, out);
}

// Round 8
// 383.634 us; speedup vs baseline: 1.2235x; 1.0169x over previous
//
#include <hip/hip_runtime.h>
#include <math.h>

#define N 8192
#define D 64
#define KS 4
#define LOG2E 1.4426950408889634f

typedef _Float16 half_t;
typedef _Float16 f16x8 __attribute__((ext_vector_type(8)));
typedef _Float16 f16x4 __attribute__((ext_vector_type(4)));
typedef float f32x4 __attribute__((ext_vector_type(4)));

#define MFMA32(a, b, c) __builtin_amdgcn_mfma_f32_16x16x32_f16((a), (b), (c), 0, 0, 0)

// Fragment-major layouts (hot-loop loads are base + lane*16B):
//  Qf,Kf [tile32][ks][tau][hl][lane][8] : elem (row=tile*32+tau*16+c16, col=ks*32+quad*8+j)
//  Zf    [tile32][dt][lane][8]          : elem (row=tile*32+quad*8+j, d=dt*16+c16)  HI only
//  XYf   [tile16][ks][lane][8]          : elem (row=tile*16+c16, col=ks*32+quad*8+j) HI only
// where lane = quad*16 + c16.
//
// Session ledger (measured): R4=386.2 best; attn=83 (R5), rbf=35 (R6);
// harness-fixed ~254 of dur_us. R1/R2 structural attn rewrites regressed;
// R7 load-order hoists neutral. R8 = R4 + attn block-ID pairing remap ONLY:
// make co-resident block pairs {d, d+256} share (side, z-quarter) with
// adjacent x, so both scan the IDENTICAL K/Z tile sequence -> trailing
// block's loads hit L1 -> per-CU L2 request traffic for K/Z ~halves.
// Bijective remap => outputs identical; worst case a no-op relabeling.

// ---------------------------------------------------------------------------
// K1: Qf = (X@Wq)*0.125*log2e, Kf = X@Wk, both f16 hi/lo frag-major.
// (EXACT R0 version — rr-outer.)
// ---------------------------------------------------------------------------
__global__ __launch_bounds__(256) void proj_kernel(
    const float* __restrict__ Wq, const float* __restrict__ Wk,
    const float* __restrict__ X, const float* __restrict__ Y,
    half_t* __restrict__ Qfx, half_t* __restrict__ Qfy,
    half_t* __restrict__ Kfx, half_t* __restrict__ Kfy)
{
    __shared__ float sWq[64][64];
    __shared__ float sWk[64][64];
    __shared__ float sIn[16][64];
    const int t = threadIdx.x;
#pragma unroll
    for (int p = 0; p < 16; ++p) {
        int idx = p * 256 + t;
        sWq[idx >> 6][idx & 63] = Wq[idx];
        sWk[idx >> 6][idx & 63] = Wk[idx];
    }
    const int R0 = blockIdx.x * 16;
    const float* src; half_t* dqf; half_t* dkf; int r0;
    if (R0 < N) { src = X; dqf = Qfx; dkf = Kfx; r0 = R0; }
    else        { src = Y; dqf = Qfy; dkf = Kfy; r0 = R0 - N; }
#pragma unroll
    for (int p = 0; p < 4; ++p) {
        int idx = p * 256 + t;
        sIn[idx >> 6][idx & 63] = src[(size_t)r0 * D + idx];
    }
    __syncthreads();
    const int c = t & 63;
    const int rb = t >> 6;
    const int ksi = c >> 5, quadi = (c >> 3) & 3, j = c & 7;
#pragma unroll
    for (int rr = 0; rr < 4; ++rr) {
        int r = rr * 4 + rb;
        float aq = 0.f, ak = 0.f;
#pragma unroll
        for (int k = 0; k < 64; ++k) {
            float xv = sIn[r][k];
            aq = fmaf(xv, sWq[k][c], aq);
            ak = fmaf(xv, sWk[k][c], ak);
        }
        aq *= (0.125f * LOG2E);
        int rg = r0 + r;
        int tile = rg >> 5, tau = (rg >> 4) & 1, c16l = rg & 15;
        size_t idx = (size_t)tile * 4096 + ksi * 2048 + tau * 1024
                   + (quadi * 16 + c16l) * 8 + j;
        half_t qhh = (half_t)aq;
        dqf[idx]       = qhh;
        dqf[idx + 512] = (half_t)(aq - (float)qhh);
        half_t khh = (half_t)ak;
        dkf[idx]       = khh;
        dkf[idx + 512] = (half_t)(ak - (float)khh);
    }
}

// ---------------------------------------------------------------------------
// K2: Zf prep (transposed input, f16 HI only, frag-major). grid (N/32, 2).
// ---------------------------------------------------------------------------
__global__ __launch_bounds__(256) void ztprep_kernel(
    const float* __restrict__ X, const float* __restrict__ Y,
    half_t* __restrict__ Zfx, half_t* __restrict__ Zfy)
{
    const int t = threadIdx.x;
    const int tile = blockIdx.x;
    const float* src = blockIdx.y ? Y : X;
    half_t* dst = blockIdx.y ? Zfy : Zfx;
    const int dt = t >> 6, lane = t & 63;
    const int quad = lane >> 4, c16 = lane & 15;
    f16x8 h;
#pragma unroll
    for (int j = 0; j < 8; ++j)
        h[j] = (half_t)src[(size_t)(tile * 32 + quad * 8 + j) * D + dt * 16 + c16];
    *(f16x8*)&dst[(size_t)tile * 2048 + dt * 512 + lane * 8] = h;
}

// ---------------------------------------------------------------------------
// K3: flash attention — R4 structure + body (4-wave 256-thread blocks, 2/CU,
// register ping-pong K prefetch, zero barriers, setprio on MFMA clusters).
// R8 delta: bijective block-ID remap so dispatch positions d and d+256
// (typical co-resident pair under round-robin placement) get the same
// (side, z-quarter) and adjacent x -> both blocks on a CU stream the SAME
// K/Z tiles in near-lockstep -> trailing block hits L1. Outputs identical.
// ---------------------------------------------------------------------------
__global__ __launch_bounds__(256, 2) void attn_kernel(
    const half_t* __restrict__ Qfx, const half_t* __restrict__ Qfy,
    const half_t* __restrict__ Kfx, const half_t* __restrict__ Kfy,
    const half_t* __restrict__ Zfx, const half_t* __restrict__ Zfy,
    half_t* __restrict__ Opart, float* __restrict__ mpart, float* __restrict__ lpart)
{
    // ---- R8 pairing remap (bijection on 512 blocks) ----
    // dispatch d = x + 64*y + 128*z ; s=d>>8, r=d&255.
    // logical: yz = r>>5 (8 cohorts) -> side=yz&1, zq=yz>>1 ;
    //          xlog = 2*(r&31) + s  (pair {d,d+256} -> adjacent xlog).
    const int d = blockIdx.x + 64 * blockIdx.y + 128 * blockIdx.z;
    const int s = d >> 8, r = d & 255;
    const int yz = r >> 5;
    const int side = yz & 1;
    const int zq = yz >> 1;
    const int xlog = ((r & 31) << 1) | s;

    const half_t* Qf = side ? Qfy : Qfx;
    const half_t* Kf = side ? Kfy : Kfx;
    const half_t* Zf = side ? Zfy : Zfx;
    const int t = threadIdx.x, w = t >> 6, lane = t & 63;
    const int c16 = lane & 15, quad = lane >> 4;
    const int q0 = xlog * 128 + w * 32;
    const int tile0 = zq * (N / KS / 32);
    const int ITERS = (N / KS) / 32;   // 64

    __shared__ half_t Pbuf[4][32][40];   // [wave][q][kv(+pad)] hi only
    half_t (*Phi)[40] = Pbuf[w];

    f16x8 qh[2][2], ql[2][2];   // [qg][ks]
    {
        const half_t* qb = Qf + (size_t)(q0 >> 5) * 4096 + lane * 8;
#pragma unroll
        for (int ks = 0; ks < 2; ++ks)
#pragma unroll
            for (int qg = 0; qg < 2; ++qg) {
                qh[qg][ks] = *(const f16x8*)&qb[ks * 2048 + qg * 1024];
                ql[qg][ks] = *(const f16x8*)&qb[ks * 2048 + qg * 1024 + 512];
            }
    }

    f32x4 ot[4][2] = {};      // O^T accumulators [dt][qg]
    f32x4 lacc[2] = {};       // l accumulators via ones-row MFMA
    float m_run[2] = {-INFINITY, -INFINITY};
    f16x8 ones;
#pragma unroll
    for (int i = 0; i < 8; ++i) ones[i] = (half_t)1.0f;

    f16x8 kAh[2][2], kAl[2][2], kBh[2][2], kBl[2][2];   // ping-pong K frags
    f32x4 stA[2][2], stB[2][2];                          // double-buffered S^T

    auto loadK = [&](int tile, f16x8 (&kh)[2][2], f16x8 (&kl)[2][2]) {
        const half_t* b = Kf + (size_t)tile * 4096 + lane * 8;
#pragma unroll
        for (int ks = 0; ks < 2; ++ks)
#pragma unroll
            for (int tau = 0; tau < 2; ++tau) {
                kh[ks][tau] = *(const f16x8*)&b[ks * 2048 + tau * 1024];
                kl[ks][tau] = *(const f16x8*)&b[ks * 2048 + tau * 1024 + 512];
            }
    };
    auto doS = [&](f32x4 (&st)[2][2], f16x8 (&kh)[2][2], f16x8 (&kl)[2][2]) {
        const f32x4 zero = {};
#pragma unroll
        for (int qg = 0; qg < 2; ++qg)
#pragma unroll
            for (int tau = 0; tau < 2; ++tau) st[qg][tau] = zero;
        __builtin_amdgcn_s_setprio(1);
#pragma unroll
        for (int ks = 0; ks < 2; ++ks)
#pragma unroll
            for (int tau = 0; tau < 2; ++tau)
#pragma unroll
                for (int qg = 0; qg < 2; ++qg) {
                    st[qg][tau] = MFMA32(kh[ks][tau], qh[qg][ks], st[qg][tau]);
                    st[qg][tau] = MFMA32(kh[ks][tau], ql[qg][ks], st[qg][tau]);
                    st[qg][tau] = MFMA32(kl[ks][tau], qh[qg][ks], st[qg][tau]);
                }
        __builtin_amdgcn_s_setprio(0);
    };

    auto body = [&](int tt, f32x4 (&stCur)[2][2], f32x4 (&stNext)[2][2],
                    f16x8 (&kNh)[2][2], f16x8 (&kNl)[2][2],
                    f16x8 (&kRh)[2][2], f16x8 (&kRl)[2][2]) {
        if (tt + 1 < ITERS) doS(stNext, kNh, kNl);           // S(t+1) in background
        if (tt + 2 < ITERS) loadK(tile0 + tt + 2, kRh, kRl); // K(t+2) in flight
        const half_t* zb = Zf + (size_t)(tile0 + tt) * 2048 + lane * 8;
        f16x8 zh[4];
#pragma unroll
        for (int dt = 0; dt < 4; ++dt)
            zh[dt] = *(const f16x8*)&zb[dt * 512];
        // ---- online softmax (exp2 domain), P hi-only ----
#pragma unroll
        for (int qg = 0; qg < 2; ++qg) {
            float mt = fmaxf(fmaxf(fmaxf(stCur[qg][0][0], stCur[qg][0][1]),
                                   fmaxf(stCur[qg][0][2], stCur[qg][0][3])),
                             fmaxf(fmaxf(stCur[qg][1][0], stCur[qg][1][1]),
                                   fmaxf(stCur[qg][1][2], stCur[qg][1][3])));
            mt = fmaxf(mt, __shfl_xor(mt, 16));
            mt = fmaxf(mt, __shfl_xor(mt, 32));
            float mn = fmaxf(m_run[qg], mt);
            float al = exp2f(m_run[qg] - mn);
            m_run[qg] = mn;
#pragma unroll
            for (int tau = 0; tau < 2; ++tau) {
                f16x4 h4;
#pragma unroll
                for (int r4 = 0; r4 < 4; ++r4)
                    h4[r4] = (half_t)exp2f(stCur[qg][tau][r4] - mn);
                *(f16x4*)&Phi[16 * qg + c16][16 * tau + 4 * quad] = h4;
            }
            lacc[qg] *= al;
#pragma unroll
            for (int dt = 0; dt < 4; ++dt) ot[dt][qg] *= al;
        }
        // ---- P B-frags from LDS, PV + l ----
        f16x8 pbh[2];
#pragma unroll
        for (int qg = 0; qg < 2; ++qg)
            pbh[qg] = *(const f16x8*)&Phi[16 * qg + c16][quad * 8];
        __builtin_amdgcn_s_setprio(1);
#pragma unroll
        for (int dt = 0; dt < 4; ++dt)
#pragma unroll
            for (int qg = 0; qg < 2; ++qg)
                ot[dt][qg] = MFMA32(zh[dt], pbh[qg], ot[dt][qg]);
#pragma unroll
        for (int qg = 0; qg < 2; ++qg)
            lacc[qg] = MFMA32(ones, pbh[qg], lacc[qg]);
        __builtin_amdgcn_s_setprio(0);
    };

    loadK(tile0, kAh, kAl);
    doS(stA, kAh, kAl);                         // S(0)
    if (ITERS > 1) loadK(tile0 + 1, kBh, kBl);  // K(1)
#pragma unroll 1
    for (int tt = 0; tt < ITERS; tt += 2) {
        body(tt,     stA, stB, kBh, kBl, kAh, kAl);
        body(tt + 1, stB, stA, kAh, kAl, kBh, kBl);
    }

    // epilogue: unnormalized O (f16, relative to m_run) + m, l partials (f32)
    const size_t obase = (size_t)(side * KS + zq) * N;
#pragma unroll
    for (int qg = 0; qg < 2; ++qg) {
        int q = q0 + 16 * qg + c16;
#pragma unroll
        for (int dt = 0; dt < 4; ++dt) {
            f16x4 o4;
#pragma unroll
            for (int r4 = 0; r4 < 4; ++r4) o4[r4] = (half_t)ot[dt][qg][r4];
            *(f16x4*)&Opart[(obase + q) * D + 16 * dt + 4 * quad] = o4;
        }
        if (quad == 0) {
            mpart[obase + q] = m_run[qg];
            lpart[obase + q] = lacc[qg][0];
        }
    }
}

// ---------------------------------------------------------------------------
// K4: combine split-K partials (f16) -> Xf/Yf f16 HI-only frag-major.
// ---------------------------------------------------------------------------
__global__ __launch_bounds__(256) void combine_kernel(
    const half_t* __restrict__ Opart, const float* __restrict__ mpart,
    const float* __restrict__ lpart,
    half_t* __restrict__ Xf, half_t* __restrict__ Yf,
    float* __restrict__ n2x, float* __restrict__ n2y)
{
    const int side = blockIdx.y;
    const int q = blockIdx.x * 16 + (threadIdx.x >> 4);
    const int d4 = (threadIdx.x & 15) * 4;
    float m[KS], l[KS];
#pragma unroll
    for (int s = 0; s < KS; ++s) {
        size_t b = (size_t)(side * KS + s) * N + q;
        m[s] = mpart[b]; l[s] = lpart[b];
    }
    float M = -INFINITY;
#pragma unroll
    for (int s = 0; s < KS; ++s) M = fmaxf(M, m[s]);
    float L = 0.f;
    f32x4 o = {0.f, 0.f, 0.f, 0.f};
#pragma unroll
    for (int s = 0; s < KS; ++s) {
        float sc = exp2f(m[s] - M);
        L += l[s] * sc;
        f16x4 p4 = *(const f16x4*)&Opart[((size_t)(side * KS + s) * N + q) * D + d4];
#pragma unroll
        for (int i = 0; i < 4; ++i) o[i] = fmaf((float)p4[i], sc, o[i]);
    }
    const float oscale = (side ? 1.0f : 2.0f * LOG2E) / L;
    f16x4 h4;
#pragma unroll
    for (int i = 0; i < 4; ++i) h4[i] = (half_t)(o[i] * oscale);
    float sq = 0.f;
#pragma unroll
    for (int i = 0; i < 4; ++i) { float hv = (float)h4[i]; sq = fmaf(hv, hv, sq); }
#pragma unroll
    for (int off = 1; off < 16; off <<= 1) sq += __shfl_xor(sq, off);
    half_t* dst = side ? Yf : Xf;
    float*  n2  = side ? n2y : n2x;
    if ((threadIdx.x & 15) == 0)
        n2[q] = side ? sq * LOG2E : sq * (0.25f / LOG2E);
    const int tile16 = q >> 4, c16l = q & 15;
    const int ksi = d4 >> 5, quadi = (d4 >> 3) & 3, j0 = d4 & 7;
    *(f16x4*)&dst[(size_t)tile16 * 1024 + ksi * 512 + (quadi * 16 + c16l) * 8 + j0] = h4;
}

// ---------------------------------------------------------------------------
// K5: RBF via single-term f16 MFMA (consistent-points numerics), frag-major
// loads. EXACT R0 version (A=X frag, B=Y frag, scalar stores). Measured
// ~35us (R6) — at its 268MB write floor; done.
// ---------------------------------------------------------------------------
__global__ __launch_bounds__(256, 4) void rbf_kernel(
    const half_t* __restrict__ Xf, const half_t* __restrict__ Yf,
    const float* __restrict__ n2x, const float* __restrict__ n2y,
    float* __restrict__ out)
{
    const int t = threadIdx.x, w = t >> 6, lane = t & 63;
    const int c16 = lane & 15, quad = lane >> 4;
    const int X0 = blockIdx.y * 128 + (w >> 1) * 64;
    const int Y0 = blockIdx.x * 128 + (w & 1) * 64;
    float ny[4];
    f32x4 nx4[4];
#pragma unroll
    for (int yt = 0; yt < 4; ++yt) ny[yt] = n2y[Y0 + 16 * yt + c16];
#pragma unroll
    for (int xt = 0; xt < 4; ++xt)
        nx4[xt] = *(const f32x4*)&n2x[X0 + 16 * xt + 4 * quad];

    const half_t* Xb = Xf + lane * 8;
    const half_t* Yb = Yf + lane * 8;
    f32x4 acc[4][4] = {};   // [xt][yt]
#pragma unroll
    for (int ks = 0; ks < 2; ++ks) {
        f16x8 bh[4];
#pragma unroll
        for (int yt = 0; yt < 4; ++yt)
            bh[yt] = *(const f16x8*)&Yb[(size_t)((Y0 >> 4) + yt) * 1024 + ks * 512];
#pragma unroll
        for (int xt = 0; xt < 4; ++xt) {
            f16x8 ah = *(const f16x8*)&Xb[(size_t)((X0 >> 4) + xt) * 1024 + ks * 512];
#pragma unroll
            for (int yt = 0; yt < 4; ++yt)
                acc[xt][yt] = MFMA32(ah, bh[yt], acc[xt][yt]);
        }
    }
#pragma unroll
    for (int xt = 0; xt < 4; ++xt)
#pragma unroll
        for (int r = 0; r < 4; ++r) {
            int xr = X0 + 16 * xt + 4 * quad + r;
            float nx = nx4[xt][r];
#pragma unroll
            for (int yt = 0; yt < 4; ++yt) {
                float v = exp2f(acc[xt][yt][r] - nx - ny[yt]);
                out[(size_t)xr * N + Y0 + 16 * yt + c16] = v;
            }
        }
}

// ---------------------------------------------------------------------------
extern "C" void kernel_launch(void* const* d_in, const int* in_sizes, int n_in,
                              void* d_out, int out_size, void* d_ws, size_t ws_size,
                              hipStream_t stream) {
    const float* Wq = (const float*)d_in[0];
    const float* Wk = (const float*)d_in[1];
    const float* x  = (const float*)d_in[2];
    const float* y  = (const float*)d_in[3];
    float* out = (float*)d_out;

    char* p = (char*)d_ws;
    size_t used = 0;
    auto alloc = [&](size_t bytes) -> void* {
        void* r = (void*)(p + used);
        used += (bytes + 255) & ~(size_t)255;
        return r;
    };
    half_t* Qfx = (half_t*)alloc((size_t)N * D * 2 * 2);   // hi+lo frag-major
    half_t* Qfy = (half_t*)alloc((size_t)N * D * 2 * 2);
    half_t* Kfx = (half_t*)alloc((size_t)N * D * 2 * 2);
    half_t* Kfy = (half_t*)alloc((size_t)N * D * 2 * 2);
    half_t* Zfx = (half_t*)alloc((size_t)N * D * 2);       // hi only
    half_t* Zfy = (half_t*)alloc((size_t)N * D * 2);
    half_t* Xf  = (half_t*)alloc((size_t)N * D * 2);       // hi only
    half_t* Yf  = (half_t*)alloc((size_t)N * D * 2);
    float*  n2x = (float*) alloc((size_t)N * 4);
    float*  n2y = (float*) alloc((size_t)N * 4);
    half_t* Opart = (half_t*)alloc((size_t)2 * KS * N * D * 2);   // f16 partials
    float*  mpart = (float*) alloc((size_t)2 * KS * N * 4);
    float*  lpart = (float*) alloc((size_t)2 * KS * N * 4);

    proj_kernel<<<dim3(2 * N / 16), 256, 0, stream>>>(Wq, Wk, x, y,
                                                      Qfx, Qfy, Kfx, Kfy);
    ztprep_kernel<<<dim3(N / 32, 2), 256, 0, stream>>>(x, y, Zfx, Zfy);
    attn_kernel<<<dim3(N / 128, 2, KS), 256, 0, stream>>>(
        Qfx, Qfy, Kfx, Kfy, Zfx, Zfy, Opart, mpart, lpart);
    combine_kernel<<<dim3(N / 16, 2), 256, 0, stream>>>(
        Opart, mpart, lpart, Xf, Yf, n2x, n2y);
    rbf_kernel<<<dim3(N / 128, N / 128), 256, 0, stream>>>(Xf, Yf, n2x, n2y, out);
}